// Round 8
// baseline (231.307 us; speedup 1.0000x reference)
//
#include <hip/hip_runtime.h>
#include <hip/hip_bf16.h>

// Problem constants
constexpr int Bc  = 2;
constexpr int Sq  = 1024;   // query seq len
constexpr int CTX = 1024;
constexpr int Tt  = 2048;   // total kv len
constexpr int HID = 2048;
constexpr int NH  = 32;
constexpr int NKV = 8;
constexpr int HD  = 64;

typedef __bf16 bf16_t;
typedef bf16_t bf16x8 __attribute__((ext_vector_type(8)));
typedef bf16_t bf16x4 __attribute__((ext_vector_type(4)));
typedef bf16_t bf16x2 __attribute__((ext_vector_type(2)));
typedef float  f32x4  __attribute__((ext_vector_type(4)));

// ---------------------------------------------------------------------------
// async global->LDS, 16B per lane (wave-uniform LDS base + lane*16)
// ---------------------------------------------------------------------------
__device__ __forceinline__ void gload16(const bf16_t* g, bf16_t* l)
{
    __builtin_amdgcn_global_load_lds(
        (const __attribute__((address_space(1))) void*)g,
        (__attribute__((address_space(3))) void*)l, 16, 0, 0);
}

// ---------------------------------------------------------------------------
// fp32 -> bf16 elementwise convert (8 elems/thread)
// ---------------------------------------------------------------------------
__global__ __launch_bounds__(256)
void cvt_bf16(const float* __restrict__ src, bf16_t* __restrict__ dst, int n)
{
    const int i = (blockIdx.x * 256 + threadIdx.x) * 8;
    if (i >= n) return;
    const float4 a = *reinterpret_cast<const float4*>(src + i);
    const float4 b = *reinterpret_cast<const float4*>(src + i + 4);
    bf16x8 o;
    o[0] = (bf16_t)a.x; o[1] = (bf16_t)a.y; o[2] = (bf16_t)a.z; o[3] = (bf16_t)a.w;
    o[4] = (bf16_t)b.x; o[5] = (bf16_t)b.y; o[6] = (bf16_t)b.z; o[7] = (bf16_t)b.w;
    *reinterpret_cast<bf16x8*>(dst + i) = o;
}

// fused Wq|Wk|Wv convert into contiguous dst (Wqb then Wkvb)
__global__ __launch_bounds__(256)
void cvt_w3(const float* __restrict__ wq, const float* __restrict__ wk,
            const float* __restrict__ wv, bf16_t* __restrict__ dst)
{
    const int i = (blockIdx.x * 256 + threadIdx.x) * 8;
    const float* src;
    int off;
    if (i < 4194304)      { src = wq; off = i; }
    else if (i < 5242880) { src = wk; off = i - 4194304; }
    else                  { src = wv; off = i - 5242880; }
    const float4 a = *reinterpret_cast<const float4*>(src + off);
    const float4 b = *reinterpret_cast<const float4*>(src + off + 4);
    bf16x8 o;
    o[0] = (bf16_t)a.x; o[1] = (bf16_t)a.y; o[2] = (bf16_t)a.z; o[3] = (bf16_t)a.w;
    o[4] = (bf16_t)b.x; o[5] = (bf16_t)b.y; o[6] = (bf16_t)b.z; o[7] = (bf16_t)b.w;
    *reinterpret_cast<bf16x8*>(dst + i) = o;
}

// fused concat + convert: dst [B][2048][2048] = concat(tctx, hs) per batch
__global__ __launch_bounds__(256)
void cvt_concat2(const float* __restrict__ tctx, const float* __restrict__ hs,
                 bf16_t* __restrict__ dst)
{
    const int i = (blockIdx.x * 256 + threadIdx.x) * 8;   // 0 .. 8M
    const int b = i >> 22;
    const int t = (i >> 11) & 2047;
    const int c = i & 2047;
    const float* src = (t < 1024) ? (tctx + ((size_t)(b * 1024 + t) << 11) + c)
                                  : (hs   + ((size_t)(b * 1024 + (t - 1024)) << 11) + c);
    const float4 a = *reinterpret_cast<const float4*>(src);
    const float4 d = *reinterpret_cast<const float4*>(src + 4);
    bf16x8 o;
    o[0] = (bf16_t)a.x; o[1] = (bf16_t)a.y; o[2] = (bf16_t)a.z; o[3] = (bf16_t)a.w;
    o[4] = (bf16_t)d.x; o[5] = (bf16_t)d.y; o[6] = (bf16_t)d.z; o[7] = (bf16_t)d.w;
    *reinterpret_cast<bf16x8*>(dst + i) = o;
}

// ---------------------------------------------------------------------------
// Fused QKV projection GEMM v2: BM=BN=128, BK=32, 256 thr (4 waves 2x2),
// 3-buffer LDS pipeline, prefetch distance 2, counted vmcnt (never 0 in loop),
// ONE barrier per K-step. XCD-swizzled block ids (512 blocks, chunk 64).
// RMSNorm/RoPE epilogue for Q and K outputs (wave tile spans one head).
// ---------------------------------------------------------------------------
__global__ __launch_bounds__(256)
void gemm_qkv2(const bf16_t* __restrict__ Ain, const bf16_t* __restrict__ Wq_,
               bf16_t* __restrict__ Qo, bf16_t* __restrict__ KVo,
               const float* __restrict__ qg, const float* __restrict__ kg,
               const float* __restrict__ cosb, const float* __restrict__ sinb)
{
    __shared__ __align__(16) bf16_t Ads[3][4096];   // [128][32] x3
    __shared__ __align__(16) bf16_t Bds[3][4096];

    const int tid  = threadIdx.x;
    const int wave = tid >> 6;
    const int lane = tid & 63;

    // XCD-aware bijective swizzle: 512 blocks, 8 XCDs, 64-chunk.
    const int bid = blockIdx.x;
    const int swz = (bid & 7) * 64 + (bid >> 3);
    const bool isQ = swz < 256;
    int m0, n0, NN;
    const bf16_t* Bw;
    bf16_t* C;
    if (isQ) { m0 = (swz & 15) << 7; n0 = (swz >> 4) << 7; NN = 2048; Bw = Wq_;           C = Qo; }
    else     { const int kb = swz - 256;
               m0 = (kb & 31) << 7;  n0 = (kb >> 5) << 7;  NN = 1024; Bw = Wq_ + 4194304; C = KVo; }

    const int wm = (wave >> 1) << 6;   // 0,64
    const int wn = (wave & 1) << 6;    // 0,64
    const int lr = lane & 15;
    const int lg = lane >> 4;

    // staging: per wave 2 A-chunks + 2 B-chunks (16 rows x 32 cols each)
    const int sr = lane >> 2;          // 0..15
    const int sc = (lane & 3) << 3;    // 0,8,16,24
    size_t aoff[2], boff[2];
    #pragma unroll
    for (int cc = 0; cc < 2; ++cc) {
        const int am = m0 + wave * 32 + cc * 16 + sr;
        const int ar = isQ ? (((am >> 10) << 11) + 1024 + (am & 1023)) : am;
        aoff[cc] = (size_t)ar * HID + sc;
        boff[cc] = (size_t)(n0 + wave * 32 + cc * 16 + sr) * HID + sc;
    }

    f32x4 acc[4][4];
    #pragma unroll
    for (int i = 0; i < 4; ++i)
        #pragma unroll
        for (int j = 0; j < 4; ++j)
            #pragma unroll
            for (int r = 0; r < 4; ++r) acc[i][j][r] = 0.0f;

    auto STAGE = [&](int buf, int k0) {
        #pragma unroll
        for (int cc = 0; cc < 2; ++cc) {
            gload16(Ain + aoff[cc] + k0, &Ads[buf][(wave * 2 + cc) << 9]);
            gload16(Bw  + boff[cc] + k0, &Bds[buf][(wave * 2 + cc) << 9]);
        }
    };

    constexpr int nk = HID / 32;   // 64
    STAGE(0, 0);
    STAGE(1, 32);

    for (int t = 0; t < nk; ++t) {
        // wait tile t's 4 loads (tile t+1's 4 may remain in flight)
        if (t < nk - 1) asm volatile("s_waitcnt vmcnt(4)" ::: "memory");
        else            asm volatile("s_waitcnt vmcnt(0)" ::: "memory");
        __builtin_amdgcn_s_barrier();
        __builtin_amdgcn_sched_barrier(0);

        const int buf = t % 3;
        bf16x8 af[4], bfr[4];
        #pragma unroll
        for (int i = 0; i < 4; ++i) {
            af[i]  = *reinterpret_cast<const bf16x8*>(&Ads[buf][(wm + i * 16 + lr) * 32 + lg * 8]);
            bfr[i] = *reinterpret_cast<const bf16x8*>(&Bds[buf][(wn + i * 16 + lr) * 32 + lg * 8]);
        }
        asm volatile("s_waitcnt lgkmcnt(0)" ::: "memory");
        __builtin_amdgcn_sched_barrier(0);

        if (t + 2 < nk) STAGE((t + 2) % 3, (t + 2) * 32);

        __builtin_amdgcn_s_setprio(1);
        #pragma unroll
        for (int mi = 0; mi < 4; ++mi)
            #pragma unroll
            for (int ni = 0; ni < 4; ++ni)
                acc[mi][ni] = __builtin_amdgcn_mfma_f32_16x16x32_bf16(
                    af[mi], bfr[ni], acc[mi][ni], 0, 0, 0);
        __builtin_amdgcn_s_setprio(0);
    }

    // epilogue: RMSNorm + RoPE for Q part and K columns of KV part.
    const int emode = isQ ? 1 : (((n0 + wn) < 512) ? 2 : 0);
    if (emode) {
        const float* gamma = (emode == 1) ? qg : kg;
        float g4[4];
        #pragma unroll
        for (int ni = 0; ni < 4; ++ni) g4[ni] = gamma[ni * 16 + lr];

        #pragma unroll
        for (int mi = 0; mi < 4; ++mi)
            #pragma unroll
            for (int r = 0; r < 4; ++r) {
                const int m = m0 + wm + mi * 16 + lg * 4 + r;
                float ss = 0.0f;
                #pragma unroll
                for (int ni = 0; ni < 4; ++ni) ss += acc[mi][ni][r] * acc[mi][ni][r];
                ss += __shfl_xor(ss, 1);
                ss += __shfl_xor(ss, 2);
                ss += __shfl_xor(ss, 4);
                ss += __shfl_xor(ss, 8);
                const float rn = rsqrtf(ss * (1.0f / 64.0f) + 1e-6f);
                int bb, pos;
                if (emode == 1) { bb = m >> 10; pos = 1024 + (m & 1023); }
                else            { bb = m >> 11; pos = m & 2047; }
                const float* cp = cosb + (((size_t)bb * 2048 + pos) << 6);
                const float* sp = sinb + (((size_t)bb * 2048 + pos) << 6);
                float qn[4];
                #pragma unroll
                for (int ni = 0; ni < 4; ++ni) qn[ni] = acc[mi][ni][r] * rn * g4[ni];
                #pragma unroll
                for (int ni = 0; ni < 4; ++ni) {
                    const float rot = (ni < 2) ? -qn[ni + 2] : qn[ni - 2];
                    acc[mi][ni][r] = qn[ni] * cp[ni * 16 + lr] + rot * sp[ni * 16 + lr];
                }
            }
    }

    #pragma unroll
    for (int mi = 0; mi < 4; ++mi)
        #pragma unroll
        for (int r = 0; r < 4; ++r) {
            const int m = m0 + wm + mi * 16 + lg * 4 + r;
            bf16_t* crow = C + (size_t)m * NN + n0 + wn + lr;
            crow[0]  = (bf16_t)acc[mi][0][r];
            crow[16] = (bf16_t)acc[mi][1][r];
            crow[32] = (bf16_t)acc[mi][2][r];
            crow[48] = (bf16_t)acc[mi][3][r];
        }
}

// ---------------------------------------------------------------------------
// Out-projection GEMM v2: C[m,n] = sum_k A[m,k]*B[n,k], fp32 C.
// M=N=K=2048 hardcoded. BM=64, BN=128, BK=32, same 3-buf counted-vmcnt
// pipeline, XCD swizzle (512 blocks, chunk 64).
// ---------------------------------------------------------------------------
__global__ __launch_bounds__(256)
void gemm_out2(const bf16_t* __restrict__ A, const bf16_t* __restrict__ Bw,
               float* __restrict__ C)
{
    __shared__ __align__(16) bf16_t Ads[3][2048];   // [64][32] x3
    __shared__ __align__(16) bf16_t Bds[3][4096];   // [128][32] x3

    const int tid  = threadIdx.x;
    const int wave = tid >> 6;
    const int lane = tid & 63;

    const int bid = blockIdx.x;
    const int swz = (bid & 7) * 64 + (bid >> 3);
    const int m0 = (swz & 31) << 6;   // 32 m-blocks
    const int n0 = (swz >> 5) << 7;   // 16 n-blocks

    const int wm = (wave >> 1) << 5;  // 0,32
    const int wn = (wave & 1) << 6;   // 0,64
    const int lr = lane & 15;
    const int lg = lane >> 4;

    const int sr = lane >> 2;
    const int sc = (lane & 3) << 3;

    const size_t aoff  = (size_t)(m0 + wave * 16 + sr) * HID + sc;
    size_t boff[2];
    #pragma unroll
    for (int cc = 0; cc < 2; ++cc)
        boff[cc] = (size_t)(n0 + wave * 32 + cc * 16 + sr) * HID + sc;

    f32x4 acc[2][4];
    #pragma unroll
    for (int i = 0; i < 2; ++i)
        #pragma unroll
        for (int j = 0; j < 4; ++j)
            #pragma unroll
            for (int r = 0; r < 4; ++r) acc[i][j][r] = 0.0f;

    auto STAGE = [&](int buf, int k0) {
        gload16(A + aoff + k0, &Ads[buf][wave << 9]);
        #pragma unroll
        for (int cc = 0; cc < 2; ++cc)
            gload16(Bw + boff[cc] + k0, &Bds[buf][(wave * 2 + cc) << 9]);
    };

    constexpr int nk = HID / 32;   // 64
    STAGE(0, 0);
    STAGE(1, 32);

    for (int t = 0; t < nk; ++t) {
        if (t < nk - 1) asm volatile("s_waitcnt vmcnt(3)" ::: "memory");
        else            asm volatile("s_waitcnt vmcnt(0)" ::: "memory");
        __builtin_amdgcn_s_barrier();
        __builtin_amdgcn_sched_barrier(0);

        const int buf = t % 3;
        bf16x8 af[2], bfr[4];
        #pragma unroll
        for (int i = 0; i < 2; ++i)
            af[i]  = *reinterpret_cast<const bf16x8*>(&Ads[buf][(wm + i * 16 + lr) * 32 + lg * 8]);
        #pragma unroll
        for (int i = 0; i < 4; ++i)
            bfr[i] = *reinterpret_cast<const bf16x8*>(&Bds[buf][(wn + i * 16 + lr) * 32 + lg * 8]);
        asm volatile("s_waitcnt lgkmcnt(0)" ::: "memory");
        __builtin_amdgcn_sched_barrier(0);

        if (t + 2 < nk) STAGE((t + 2) % 3, (t + 2) * 32);

        __builtin_amdgcn_s_setprio(1);
        #pragma unroll
        for (int mi = 0; mi < 2; ++mi)
            #pragma unroll
            for (int ni = 0; ni < 4; ++ni)
                acc[mi][ni] = __builtin_amdgcn_mfma_f32_16x16x32_bf16(
                    af[mi], bfr[ni], acc[mi][ni], 0, 0, 0);
        __builtin_amdgcn_s_setprio(0);
    }

    #pragma unroll
    for (int mi = 0; mi < 2; ++mi)
        #pragma unroll
        for (int r = 0; r < 4; ++r) {
            const int m = m0 + wm + mi * 16 + lg * 4 + r;
            float* crow = C + (size_t)m * 2048 + n0 + wn + lr;
            crow[0]  = acc[mi][0][r];
            crow[16] = acc[mi][1][r];
            crow[32] = acc[mi][2][r];
            crow[48] = acc[mi][3][r];
        }
}

// ---------------------------------------------------------------------------
// bf16 MFMA flash attention, split-T partials.
// 8 waves (512 thr), QBLK=128, KV tile 64, double-buffered K/V with register
// prefetch, ONE barrier per tile. Fixed-max softmax (scores provably < 48
// in log2 domain): no running max, no rescale => partials from the two
// T-halves combine by simple addition. P exchanged in-register (4x4
// lane-block transpose via shfl_xor, verified r5) => no P LDS, 34.8KB total,
// 4 blocks/CU. Grid: (B*NH, Sq/128, 2). Writes unnormalized bf16 partial O
// and per-row l to workspace.
// ---------------------------------------------------------------------------
__global__ __launch_bounds__(512, 8)
void flash_mfma(const bf16_t* __restrict__ Qb, const bf16_t* __restrict__ KVb,
                bf16_t* __restrict__ P0, bf16_t* __restrict__ P1,
                float* __restrict__ lbuf)
{
    const int bh = blockIdx.x;
    const int b  = bh >> 5;
    const int h  = bh & 31;
    const int g  = h >> 2;
    const int q0 = blockIdx.y << 7;
    const int half = blockIdx.z;
    const int tid  = threadIdx.x;
    const int wave = tid >> 6;
    const int lane = tid & 63;
    const int lr = lane & 15;
    const int lg = lane >> 4;

    __shared__ __align__(16) bf16_t Kd[2][64][68];      // [k][d]
    __shared__ __align__(16) bf16_t Vd[2][64][68];      // [d][t]

    // staging assignment (block-wide, 512 threads)
    const int kr = tid >> 3;            // K row 0..63
    const int kc = (tid & 7) << 3;      // K col 0,8,..,56
    const int tp = tid >> 4;            // V t-pair 0..31
    const int d0 = (tid & 15) << 2;     // V d-group

    const size_t kbase = (size_t)(b * Tt) * 1024 + g * 64;
    const int t0s = half << 10;         // this block's key range start

    bf16x8 qf[2];
    {
        const bf16_t* qp = Qb + (size_t)(b * Sq + q0 + wave * 16 + lr) * 2048 + h * 64 + lg * 8;
        qf[0] = *reinterpret_cast<const bf16x8*>(qp);
        qf[1] = *reinterpret_cast<const bf16x8*>(qp + 32);
    }

    float ls = 0.0f;
    f32x4 oacc[4];
    #pragma unroll
    for (int dt = 0; dt < 4; ++dt)
        #pragma unroll
        for (int j = 0; j < 4; ++j) oacc[dt][j] = 0.0f;

    bf16x8 kreg;
    bf16x4 vr0, vr1;
    {
        kreg = *reinterpret_cast<const bf16x8*>(KVb + kbase + (size_t)(t0s + kr) * 1024 + kc);
        const bf16_t* vp = KVb + kbase + (size_t)(t0s + tp * 2) * 1024 + 512 + d0;
        vr0 = *reinterpret_cast<const bf16x4*>(vp);
        vr1 = *reinterpret_cast<const bf16x4*>(vp + 1024);
    }
    *reinterpret_cast<bf16x8*>(&Kd[0][kr][kc]) = kreg;
    #pragma unroll
    for (int j = 0; j < 4; ++j) {
        bf16x2 w; w[0] = vr0[j]; w[1] = vr1[j];
        *reinterpret_cast<bf16x2*>(&Vd[0][d0 + j][tp * 2]) = w;
    }
    __syncthreads();

    constexpr float Cs = 0.125f * 1.44269504088896f;   // scale * log2(e)
    constexpr float Ms = 48.0f;                        // fixed max bound
    const bool bq    = (lg & 2) != 0;
    const bool keepX = (lg == 0) || (lg == 3);
    const bool odd   = (lg & 1) != 0;
    int cur = 0;

    for (int t0 = t0s; t0 < t0s + 1024; t0 += 64) {
        const bool more = (t0 + 64 < t0s + 1024);
        if (more) {
            const size_t tb = kbase + (size_t)(t0 + 64) * 1024;
            kreg = *reinterpret_cast<const bf16x8*>(KVb + tb + (size_t)kr * 1024 + kc);
            const bf16_t* vp = KVb + tb + (size_t)(tp * 2) * 1024 + 512 + d0;
            vr0 = *reinterpret_cast<const bf16x4*>(vp);
            vr1 = *reinterpret_cast<const bf16x4*>(vp + 1024);
        }

        // QK^T (swapped): S^T = K * Q^T
        f32x4 sc[4];
        __builtin_amdgcn_s_setprio(1);
        #pragma unroll
        for (int kt = 0; kt < 4; ++kt) {
            #pragma unroll
            for (int j = 0; j < 4; ++j) sc[kt][j] = 0.0f;
            const bf16x8 kf0 = *reinterpret_cast<const bf16x8*>(&Kd[cur][kt * 16 + lr][lg * 8]);
            const bf16x8 kf1 = *reinterpret_cast<const bf16x8*>(&Kd[cur][kt * 16 + lr][32 + lg * 8]);
            sc[kt] = __builtin_amdgcn_mfma_f32_16x16x32_bf16(kf0, qf[0], sc[kt], 0, 0, 0);
            sc[kt] = __builtin_amdgcn_mfma_f32_16x16x32_bf16(kf1, qf[1], sc[kt], 0, 0, 0);
        }
        __builtin_amdgcn_s_setprio(0);

        // fixed-max softmax: P = exp2(s*Cs - 48); pack bf16 into cc[kt]
        uint2 cc[4];
        #pragma unroll
        for (int kt = 0; kt < 4; ++kt) {
            bf16x4 pw;
            #pragma unroll
            for (int j = 0; j < 4; ++j) {
                const float e = exp2f(fmaf(sc[kt][j], Cs, -Ms));
                ls += e;
                pw[j] = (bf16_t)e;
            }
            cc[kt] = *reinterpret_cast<uint2*>(&pw);
        }

        // in-register P exchange: 4x4 block transpose across lanes {lr+16*lg}
        uint2 X0 = bq ? cc[1] : cc[0];
        uint2 X1 = bq ? cc[3] : cc[2];
        uint2 S0 = bq ? cc[0] : cc[1];
        uint2 S1 = bq ? cc[2] : cc[3];
        uint2 Y0, Y1;
        Y0.x = __shfl_xor(S0.x, 32); Y0.y = __shfl_xor(S0.y, 32);
        Y1.x = __shfl_xor(S1.x, 32); Y1.y = __shfl_xor(S1.y, 32);
        uint2 T0 = keepX ? Y0 : X0, T1 = keepX ? Y1 : X1;
        uint2 K0 = keepX ? X0 : Y0, K1 = keepX ? X1 : Y1;
        uint2 U0, U1;
        U0.x = __shfl_xor(T0.x, 16); U0.y = __shfl_xor(T0.y, 16);
        U1.x = __shfl_xor(T1.x, 16); U1.y = __shfl_xor(T1.y, 16);
        uint2 lo0 = odd ? U0 : K0, hi0 = odd ? K0 : U0;
        uint2 lo1 = odd ? U1 : K1, hi1 = odd ? K1 : U1;
        uint4 pb0u = {lo0.x, lo0.y, hi0.x, hi0.y};
        uint4 pb1u = {lo1.x, lo1.y, hi1.x, hi1.y};
        const bf16x8 pb0 = *reinterpret_cast<bf16x8*>(&pb0u);
        const bf16x8 pb1 = *reinterpret_cast<bf16x8*>(&pb1u);

        // PV: O^T = V^T * P^T
        __builtin_amdgcn_s_setprio(1);
        #pragma unroll
        for (int dt = 0; dt < 4; ++dt) {
            const bf16x8 vf0 = *reinterpret_cast<const bf16x8*>(&Vd[cur][dt * 16 + lr][lg * 8]);
            const bf16x8 vf1 = *reinterpret_cast<const bf16x8*>(&Vd[cur][dt * 16 + lr][32 + lg * 8]);
            oacc[dt] = __builtin_amdgcn_mfma_f32_16x16x32_bf16(vf0, pb0, oacc[dt], 0, 0, 0);
            oacc[dt] = __builtin_amdgcn_mfma_f32_16x16x32_bf16(vf1, pb1, oacc[dt], 0, 0, 0);
        }
        __builtin_amdgcn_s_setprio(0);

        // stage next tile into the other buffer; single barrier per tile
        if (more) {
            *reinterpret_cast<bf16x8*>(&Kd[cur ^ 1][kr][kc]) = kreg;
            #pragma unroll
            for (int j = 0; j < 4; ++j) {
                bf16x2 w; w[0] = vr0[j]; w[1] = vr1[j];
                *reinterpret_cast<bf16x2*>(&Vd[cur ^ 1][d0 + j][tp * 2]) = w;
            }
            __syncthreads();
        }
        cur ^= 1;
    }

    // write unnormalized partial O (bf16) + l
    ls += __shfl_xor(ls, 16);
    ls += __shfl_xor(ls, 32);
    const int r = (bh << 10) + q0 + (wave << 4) + lr;
    bf16_t* po = (half ? P1 : P0) + ((size_t)r << 6) + lg * 4;
    #pragma unroll
    for (int dt = 0; dt < 4; ++dt) {
        bf16x4 o;
        #pragma unroll
        for (int j = 0; j < 4; ++j) o[j] = (bf16_t)oacc[dt][j];
        *reinterpret_cast<bf16x4*>(po + dt * 16) = o;
    }
    if (lane < 16) lbuf[(half << 16) + r] = ls;
}

// ---------------------------------------------------------------------------
// combine the two T-half partials: Qb[row] = (P0 + P1) / (l0 + l1)
// row r = ((b*32+h)*1024+q); dest Qb[(b*1024+q)*2048 + h*64 + d]
// ---------------------------------------------------------------------------
__global__ __launch_bounds__(256)
void combine2(const bf16_t* __restrict__ p0, const bf16_t* __restrict__ p1,
              const float* __restrict__ lb, bf16_t* __restrict__ Qb)
{
    const int i = (blockIdx.x * 256 + threadIdx.x) * 8;   // 0 .. 4,194,304
    const int row = i >> 6;
    const float inv = 1.0f / (lb[row] + lb[65536 + row]);
    const bf16x8 a = *reinterpret_cast<const bf16x8*>(p0 + i);
    const bf16x8 c = *reinterpret_cast<const bf16x8*>(p1 + i);
    bf16x8 o;
    #pragma unroll
    for (int j = 0; j < 8; ++j)
        o[j] = (bf16_t)(((float)a[j] + (float)c[j]) * inv);
    const int bq = row >> 15, h = (row >> 10) & 31, q = row & 1023;
    *reinterpret_cast<bf16x8*>(
        Qb + ((size_t)((bq << 10) + q) << 11) + h * 64 + (i & 63)) = o;
}

// ---------------------------------------------------------------------------
extern "C" void kernel_launch(void* const* d_in, const int* in_sizes, int n_in,
                              void* d_out, int out_size, void* d_ws, size_t ws_size,
                              hipStream_t stream)
{
    const float* hs   = (const float*)d_in[0];
    const float* tctx = (const float*)d_in[1];
    const float* cosb = (const float*)d_in[2];
    const float* sinb = (const float*)d_in[3];
    const float* Wq   = (const float*)d_in[4];
    const float* Wk   = (const float*)d_in[5];
    const float* Wv   = (const float*)d_in[6];
    const float* Wo   = (const float*)d_in[7];
    const float* qg   = (const float*)d_in[8];
    const float* kg   = (const float*)d_in[9];
    float* out = (float*)d_out;

    // workspace layout (bf16 elems): total 23,068,672 elems = 46.1 MB
    bf16_t* W     = (bf16_t*)d_ws;
    bf16_t* kvinb = W;                    // [B][2048][2048] concat: 8,388,608
    bf16_t* Wqb   = kvinb + 8388608;      // Wq (4,194,304) + Wkv (2,097,152)
    bf16_t* Qb    = Wqb + 6291456;        // q buffer: 4,194,304
    bf16_t* KVb   = Qb + 4194304;         // k|v: 4,194,304
    // regions reused after gemm_qkv2 consumes them:
    bf16_t* Wob   = kvinb;                // Wo bf16 (first half of kvinb)
    bf16_t* Po0   = Wqb;                  // flash partial half0 (over Wq weights)
    bf16_t* Po1   = kvinb + 4194304;      // flash partial half1 (2nd half of kvinb)
    float*  lbuf  = (float*)(Wqb + 4194304);  // 131072 f32 (over Wkv weights)

    // converts
    cvt_concat2<<<4096, 256, 0, stream>>>(tctx, hs, kvinb);
    cvt_w3<<<3072, 256, 0, stream>>>(Wq, Wk, Wv, Wqb);

    // fused Q + KV projections with RMSNorm/RoPE epilogue (pipelined, XCD-swz)
    gemm_qkv2<<<512, 256, 0, stream>>>(kvinb, Wqb, Qb, KVb, qg, kg, cosb, sinb);

    // convert Wo into kvinb's space
    cvt_bf16<<<2048, 256, 0, stream>>>(Wo, Wob, 4194304);

    // flash attention, split-T partials (grid.z = half)
    flash_mfma<<<dim3(Bc * NH, Sq / 128, 2), 512, 0, stream>>>(Qb, KVb, Po0, Po1, lbuf);

    // combine halves -> bf16 attn into Qb
    combine2<<<2048, 256, 0, stream>>>(Po0, Po1, lbuf, Qb);

    // output projection: attn(bf16) @ Wo^T -> fp32 out
    gemm_out2<<<512, 256, 0, stream>>>(Qb, Wob, out);
}

// Round 9
// 170.449 us; speedup vs baseline: 1.3570x; 1.3570x over previous
//
#include <hip/hip_runtime.h>
#include <hip/hip_bf16.h>

// Problem constants
constexpr int Bc  = 2;
constexpr int Sq  = 1024;   // query seq len
constexpr int CTX = 1024;
constexpr int Tt  = 2048;   // total kv len
constexpr int HID = 2048;
constexpr int NH  = 32;
constexpr int NKV = 8;
constexpr int HD  = 64;

typedef __bf16 bf16_t;
typedef bf16_t bf16x8 __attribute__((ext_vector_type(8)));
typedef bf16_t bf16x4 __attribute__((ext_vector_type(4)));
typedef bf16_t bf16x2 __attribute__((ext_vector_type(2)));
typedef float  f32x4  __attribute__((ext_vector_type(4)));

// ---------------------------------------------------------------------------
// async global->LDS, 16B per lane (wave-uniform LDS base + lane*16)
// ---------------------------------------------------------------------------
__device__ __forceinline__ void gload16(const bf16_t* g, bf16_t* l)
{
    __builtin_amdgcn_global_load_lds(
        (const __attribute__((address_space(1))) void*)g,
        (__attribute__((address_space(3))) void*)l, 16, 0, 0);
}

// ---------------------------------------------------------------------------
// fp32 -> bf16 elementwise convert (8 elems/thread)
// ---------------------------------------------------------------------------
__global__ __launch_bounds__(256)
void cvt_bf16(const float* __restrict__ src, bf16_t* __restrict__ dst, int n)
{
    const int i = (blockIdx.x * 256 + threadIdx.x) * 8;
    if (i >= n) return;
    const float4 a = *reinterpret_cast<const float4*>(src + i);
    const float4 b = *reinterpret_cast<const float4*>(src + i + 4);
    bf16x8 o;
    o[0] = (bf16_t)a.x; o[1] = (bf16_t)a.y; o[2] = (bf16_t)a.z; o[3] = (bf16_t)a.w;
    o[4] = (bf16_t)b.x; o[5] = (bf16_t)b.y; o[6] = (bf16_t)b.z; o[7] = (bf16_t)b.w;
    *reinterpret_cast<bf16x8*>(dst + i) = o;
}

// fused Wq|Wk|Wv convert into contiguous dst (Wqb then Wkvb)
__global__ __launch_bounds__(256)
void cvt_w3(const float* __restrict__ wq, const float* __restrict__ wk,
            const float* __restrict__ wv, bf16_t* __restrict__ dst)
{
    const int i = (blockIdx.x * 256 + threadIdx.x) * 8;
    const float* src;
    int off;
    if (i < 4194304)      { src = wq; off = i; }
    else if (i < 5242880) { src = wk; off = i - 4194304; }
    else                  { src = wv; off = i - 5242880; }
    const float4 a = *reinterpret_cast<const float4*>(src + off);
    const float4 b = *reinterpret_cast<const float4*>(src + off + 4);
    bf16x8 o;
    o[0] = (bf16_t)a.x; o[1] = (bf16_t)a.y; o[2] = (bf16_t)a.z; o[3] = (bf16_t)a.w;
    o[4] = (bf16_t)b.x; o[5] = (bf16_t)b.y; o[6] = (bf16_t)b.z; o[7] = (bf16_t)b.w;
    *reinterpret_cast<bf16x8*>(dst + i) = o;
}

// fused concat + convert: dst [B][2048][2048] = concat(tctx, hs) per batch
__global__ __launch_bounds__(256)
void cvt_concat2(const float* __restrict__ tctx, const float* __restrict__ hs,
                 bf16_t* __restrict__ dst)
{
    const int i = (blockIdx.x * 256 + threadIdx.x) * 8;   // 0 .. 8M
    const int b = i >> 22;
    const int t = (i >> 11) & 2047;
    const int c = i & 2047;
    const float* src = (t < 1024) ? (tctx + ((size_t)(b * 1024 + t) << 11) + c)
                                  : (hs   + ((size_t)(b * 1024 + (t - 1024)) << 11) + c);
    const float4 a = *reinterpret_cast<const float4*>(src);
    const float4 d = *reinterpret_cast<const float4*>(src + 4);
    bf16x8 o;
    o[0] = (bf16_t)a.x; o[1] = (bf16_t)a.y; o[2] = (bf16_t)a.z; o[3] = (bf16_t)a.w;
    o[4] = (bf16_t)d.x; o[5] = (bf16_t)d.y; o[6] = (bf16_t)d.z; o[7] = (bf16_t)d.w;
    *reinterpret_cast<bf16x8*>(dst + i) = o;
}

// ---------------------------------------------------------------------------
// Fused QKV projection GEMM v2: BM=BN=128, BK=32, 256 thr (4 waves 2x2),
// 3-buffer LDS pipeline, prefetch distance 2, counted vmcnt (never 0 in loop),
// ONE barrier per K-step. XCD-swizzled block ids (512 blocks, chunk 64).
// RMSNorm/RoPE epilogue for Q and K outputs (wave tile spans one head).
// ---------------------------------------------------------------------------
__global__ __launch_bounds__(256)
void gemm_qkv2(const bf16_t* __restrict__ Ain, const bf16_t* __restrict__ Wq_,
               bf16_t* __restrict__ Qo, bf16_t* __restrict__ KVo,
               const float* __restrict__ qg, const float* __restrict__ kg,
               const float* __restrict__ cosb, const float* __restrict__ sinb)
{
    __shared__ __align__(16) bf16_t Ads[3][4096];   // [128][32] x3
    __shared__ __align__(16) bf16_t Bds[3][4096];

    const int tid  = threadIdx.x;
    const int wave = tid >> 6;
    const int lane = tid & 63;

    // XCD-aware bijective swizzle: 512 blocks, 8 XCDs, 64-chunk.
    const int bid = blockIdx.x;
    const int swz = (bid & 7) * 64 + (bid >> 3);
    const bool isQ = swz < 256;
    int m0, n0, NN;
    const bf16_t* Bw;
    bf16_t* C;
    if (isQ) { m0 = (swz & 15) << 7; n0 = (swz >> 4) << 7; NN = 2048; Bw = Wq_;           C = Qo; }
    else     { const int kb = swz - 256;
               m0 = (kb & 31) << 7;  n0 = (kb >> 5) << 7;  NN = 1024; Bw = Wq_ + 4194304; C = KVo; }

    const int wm = (wave >> 1) << 6;   // 0,64
    const int wn = (wave & 1) << 6;    // 0,64
    const int lr = lane & 15;
    const int lg = lane >> 4;

    // staging: per wave 2 A-chunks + 2 B-chunks (16 rows x 32 cols each)
    const int sr = lane >> 2;          // 0..15
    const int sc = (lane & 3) << 3;    // 0,8,16,24
    size_t aoff[2], boff[2];
    #pragma unroll
    for (int cc = 0; cc < 2; ++cc) {
        const int am = m0 + wave * 32 + cc * 16 + sr;
        const int ar = isQ ? (((am >> 10) << 11) + 1024 + (am & 1023)) : am;
        aoff[cc] = (size_t)ar * HID + sc;
        boff[cc] = (size_t)(n0 + wave * 32 + cc * 16 + sr) * HID + sc;
    }

    f32x4 acc[4][4];
    #pragma unroll
    for (int i = 0; i < 4; ++i)
        #pragma unroll
        for (int j = 0; j < 4; ++j)
            #pragma unroll
            for (int r = 0; r < 4; ++r) acc[i][j][r] = 0.0f;

    auto STAGE = [&](int buf, int k0) {
        #pragma unroll
        for (int cc = 0; cc < 2; ++cc) {
            gload16(Ain + aoff[cc] + k0, &Ads[buf][(wave * 2 + cc) << 9]);
            gload16(Bw  + boff[cc] + k0, &Bds[buf][(wave * 2 + cc) << 9]);
        }
    };

    constexpr int nk = HID / 32;   // 64
    STAGE(0, 0);
    STAGE(1, 32);

    for (int t = 0; t < nk; ++t) {
        // wait tile t's 4 loads (tile t+1's 4 may remain in flight)
        if (t < nk - 1) asm volatile("s_waitcnt vmcnt(4)" ::: "memory");
        else            asm volatile("s_waitcnt vmcnt(0)" ::: "memory");
        __builtin_amdgcn_s_barrier();
        __builtin_amdgcn_sched_barrier(0);

        const int buf = t % 3;
        bf16x8 af[4], bfr[4];
        #pragma unroll
        for (int i = 0; i < 4; ++i) {
            af[i]  = *reinterpret_cast<const bf16x8*>(&Ads[buf][(wm + i * 16 + lr) * 32 + lg * 8]);
            bfr[i] = *reinterpret_cast<const bf16x8*>(&Bds[buf][(wn + i * 16 + lr) * 32 + lg * 8]);
        }
        asm volatile("s_waitcnt lgkmcnt(0)" ::: "memory");
        __builtin_amdgcn_sched_barrier(0);

        if (t + 2 < nk) STAGE((t + 2) % 3, (t + 2) * 32);

        __builtin_amdgcn_s_setprio(1);
        #pragma unroll
        for (int mi = 0; mi < 4; ++mi)
            #pragma unroll
            for (int ni = 0; ni < 4; ++ni)
                acc[mi][ni] = __builtin_amdgcn_mfma_f32_16x16x32_bf16(
                    af[mi], bfr[ni], acc[mi][ni], 0, 0, 0);
        __builtin_amdgcn_s_setprio(0);
    }

    // epilogue: RMSNorm + RoPE for Q part and K columns of KV part.
    const int emode = isQ ? 1 : (((n0 + wn) < 512) ? 2 : 0);
    if (emode) {
        const float* gamma = (emode == 1) ? qg : kg;
        float g4[4];
        #pragma unroll
        for (int ni = 0; ni < 4; ++ni) g4[ni] = gamma[ni * 16 + lr];

        #pragma unroll
        for (int mi = 0; mi < 4; ++mi)
            #pragma unroll
            for (int r = 0; r < 4; ++r) {
                const int m = m0 + wm + mi * 16 + lg * 4 + r;
                float ss = 0.0f;
                #pragma unroll
                for (int ni = 0; ni < 4; ++ni) ss += acc[mi][ni][r] * acc[mi][ni][r];
                ss += __shfl_xor(ss, 1);
                ss += __shfl_xor(ss, 2);
                ss += __shfl_xor(ss, 4);
                ss += __shfl_xor(ss, 8);
                const float rn = rsqrtf(ss * (1.0f / 64.0f) + 1e-6f);
                int bb, pos;
                if (emode == 1) { bb = m >> 10; pos = 1024 + (m & 1023); }
                else            { bb = m >> 11; pos = m & 2047; }
                const float* cp = cosb + (((size_t)bb * 2048 + pos) << 6);
                const float* sp = sinb + (((size_t)bb * 2048 + pos) << 6);
                float qn[4];
                #pragma unroll
                for (int ni = 0; ni < 4; ++ni) qn[ni] = acc[mi][ni][r] * rn * g4[ni];
                #pragma unroll
                for (int ni = 0; ni < 4; ++ni) {
                    const float rot = (ni < 2) ? -qn[ni + 2] : qn[ni - 2];
                    acc[mi][ni][r] = qn[ni] * cp[ni * 16 + lr] + rot * sp[ni * 16 + lr];
                }
            }
    }

    #pragma unroll
    for (int mi = 0; mi < 4; ++mi)
        #pragma unroll
        for (int r = 0; r < 4; ++r) {
            const int m = m0 + wm + mi * 16 + lg * 4 + r;
            bf16_t* crow = C + (size_t)m * NN + n0 + wn + lr;
            crow[0]  = (bf16_t)acc[mi][0][r];
            crow[16] = (bf16_t)acc[mi][1][r];
            crow[32] = (bf16_t)acc[mi][2][r];
            crow[48] = (bf16_t)acc[mi][3][r];
        }
}

// ---------------------------------------------------------------------------
// Out-projection GEMM v2: C[m,n] = sum_k A[m,k]*B[n,k], fp32 C.
// M=N=K=2048 hardcoded. BM=64, BN=128, BK=32, same 3-buf counted-vmcnt
// pipeline, XCD swizzle (512 blocks, chunk 64).
// ---------------------------------------------------------------------------
__global__ __launch_bounds__(256)
void gemm_out2(const bf16_t* __restrict__ A, const bf16_t* __restrict__ Bw,
               float* __restrict__ C)
{
    __shared__ __align__(16) bf16_t Ads[3][2048];   // [64][32] x3
    __shared__ __align__(16) bf16_t Bds[3][4096];   // [128][32] x3

    const int tid  = threadIdx.x;
    const int wave = tid >> 6;
    const int lane = tid & 63;

    const int bid = blockIdx.x;
    const int swz = (bid & 7) * 64 + (bid >> 3);
    const int m0 = (swz & 31) << 6;   // 32 m-blocks
    const int n0 = (swz >> 5) << 7;   // 16 n-blocks

    const int wm = (wave >> 1) << 5;  // 0,32
    const int wn = (wave & 1) << 6;   // 0,64
    const int lr = lane & 15;
    const int lg = lane >> 4;

    const int sr = lane >> 2;
    const int sc = (lane & 3) << 3;

    const size_t aoff  = (size_t)(m0 + wave * 16 + sr) * HID + sc;
    size_t boff[2];
    #pragma unroll
    for (int cc = 0; cc < 2; ++cc)
        boff[cc] = (size_t)(n0 + wave * 32 + cc * 16 + sr) * HID + sc;

    f32x4 acc[2][4];
    #pragma unroll
    for (int i = 0; i < 2; ++i)
        #pragma unroll
        for (int j = 0; j < 4; ++j)
            #pragma unroll
            for (int r = 0; r < 4; ++r) acc[i][j][r] = 0.0f;

    auto STAGE = [&](int buf, int k0) {
        gload16(A + aoff + k0, &Ads[buf][wave << 9]);
        #pragma unroll
        for (int cc = 0; cc < 2; ++cc)
            gload16(Bw + boff[cc] + k0, &Bds[buf][(wave * 2 + cc) << 9]);
    };

    constexpr int nk = HID / 32;   // 64
    STAGE(0, 0);
    STAGE(1, 32);

    for (int t = 0; t < nk; ++t) {
        if (t < nk - 1) asm volatile("s_waitcnt vmcnt(3)" ::: "memory");
        else            asm volatile("s_waitcnt vmcnt(0)" ::: "memory");
        __builtin_amdgcn_s_barrier();
        __builtin_amdgcn_sched_barrier(0);

        const int buf = t % 3;
        bf16x8 af[2], bfr[4];
        #pragma unroll
        for (int i = 0; i < 2; ++i)
            af[i]  = *reinterpret_cast<const bf16x8*>(&Ads[buf][(wm + i * 16 + lr) * 32 + lg * 8]);
        #pragma unroll
        for (int i = 0; i < 4; ++i)
            bfr[i] = *reinterpret_cast<const bf16x8*>(&Bds[buf][(wn + i * 16 + lr) * 32 + lg * 8]);
        asm volatile("s_waitcnt lgkmcnt(0)" ::: "memory");
        __builtin_amdgcn_sched_barrier(0);

        if (t + 2 < nk) STAGE((t + 2) % 3, (t + 2) * 32);

        __builtin_amdgcn_s_setprio(1);
        #pragma unroll
        for (int mi = 0; mi < 2; ++mi)
            #pragma unroll
            for (int ni = 0; ni < 4; ++ni)
                acc[mi][ni] = __builtin_amdgcn_mfma_f32_16x16x32_bf16(
                    af[mi], bfr[ni], acc[mi][ni], 0, 0, 0);
        __builtin_amdgcn_s_setprio(0);
    }

    #pragma unroll
    for (int mi = 0; mi < 2; ++mi)
        #pragma unroll
        for (int r = 0; r < 4; ++r) {
            const int m = m0 + wm + mi * 16 + lg * 4 + r;
            float* crow = C + (size_t)m * 2048 + n0 + wn + lr;
            crow[0]  = acc[mi][0][r];
            crow[16] = acc[mi][1][r];
            crow[32] = acc[mi][2][r];
            crow[48] = acc[mi][3][r];
        }
}

// ---------------------------------------------------------------------------
// bf16 MFMA flash attention, split-T partials.
// 8 waves (512 thr), QBLK=128, KV tile 64, double-buffered K/V with register
// prefetch, ONE barrier per tile. Fixed-max softmax (scores provably < 48
// in log2 domain): partials from the two T-halves combine by addition.
// P exchanged in-register (4x4 lane-block transpose via shfl_xor) => no P
// LDS, 34.8KB total. __launch_bounds__(512,6): 3 blocks/CU, VGPR cap 84
// (NOT (512,8): that forces <=64 VGPR and spills to scratch -> 112MB fetch,
// 355MB write, 2x slowdown; measured r8).
// Grid: (B*NH, Sq/128, 2). Writes unnormalized bf16 partial O + per-row l.
// ---------------------------------------------------------------------------
__global__ __launch_bounds__(512, 6)
void flash_mfma(const bf16_t* __restrict__ Qb, const bf16_t* __restrict__ KVb,
                bf16_t* __restrict__ P0, bf16_t* __restrict__ P1,
                float* __restrict__ lbuf)
{
    const int bh = blockIdx.x;
    const int b  = bh >> 5;
    const int h  = bh & 31;
    const int g  = h >> 2;
    const int q0 = blockIdx.y << 7;
    const int half = blockIdx.z;
    const int tid  = threadIdx.x;
    const int wave = tid >> 6;
    const int lane = tid & 63;
    const int lr = lane & 15;
    const int lg = lane >> 4;

    __shared__ __align__(16) bf16_t Kd[2][64][68];      // [k][d]
    __shared__ __align__(16) bf16_t Vd[2][64][68];      // [d][t]

    // staging assignment (block-wide, 512 threads)
    const int kr = tid >> 3;            // K row 0..63
    const int kc = (tid & 7) << 3;      // K col 0,8,..,56
    const int tp = tid >> 4;            // V t-pair 0..31
    const int d0 = (tid & 15) << 2;     // V d-group

    const size_t kbase = (size_t)(b * Tt) * 1024 + g * 64;
    const int t0s = half << 10;         // this block's key range start

    bf16x8 qf[2];
    {
        const bf16_t* qp = Qb + (size_t)(b * Sq + q0 + wave * 16 + lr) * 2048 + h * 64 + lg * 8;
        qf[0] = *reinterpret_cast<const bf16x8*>(qp);
        qf[1] = *reinterpret_cast<const bf16x8*>(qp + 32);
    }

    float ls = 0.0f;
    f32x4 oacc[4];
    #pragma unroll
    for (int dt = 0; dt < 4; ++dt)
        #pragma unroll
        for (int j = 0; j < 4; ++j) oacc[dt][j] = 0.0f;

    bf16x8 kreg;
    bf16x4 vr0, vr1;
    {
        kreg = *reinterpret_cast<const bf16x8*>(KVb + kbase + (size_t)(t0s + kr) * 1024 + kc);
        const bf16_t* vp = KVb + kbase + (size_t)(t0s + tp * 2) * 1024 + 512 + d0;
        vr0 = *reinterpret_cast<const bf16x4*>(vp);
        vr1 = *reinterpret_cast<const bf16x4*>(vp + 1024);
    }
    *reinterpret_cast<bf16x8*>(&Kd[0][kr][kc]) = kreg;
    #pragma unroll
    for (int j = 0; j < 4; ++j) {
        bf16x2 w; w[0] = vr0[j]; w[1] = vr1[j];
        *reinterpret_cast<bf16x2*>(&Vd[0][d0 + j][tp * 2]) = w;
    }
    __syncthreads();

    constexpr float Cs = 0.125f * 1.44269504088896f;   // scale * log2(e)
    constexpr float Ms = 48.0f;                        // fixed max bound
    const bool bq    = (lg & 2) != 0;
    const bool keepX = (lg == 0) || (lg == 3);
    const bool odd   = (lg & 1) != 0;
    int cur = 0;

    for (int t0 = t0s; t0 < t0s + 1024; t0 += 64) {
        const bool more = (t0 + 64 < t0s + 1024);
        if (more) {
            const size_t tb = kbase + (size_t)(t0 + 64) * 1024;
            kreg = *reinterpret_cast<const bf16x8*>(KVb + tb + (size_t)kr * 1024 + kc);
            const bf16_t* vp = KVb + tb + (size_t)(tp * 2) * 1024 + 512 + d0;
            vr0 = *reinterpret_cast<const bf16x4*>(vp);
            vr1 = *reinterpret_cast<const bf16x4*>(vp + 1024);
        }

        // QK^T (swapped): S^T = K * Q^T
        f32x4 sc[4];
        __builtin_amdgcn_s_setprio(1);
        #pragma unroll
        for (int kt = 0; kt < 4; ++kt) {
            #pragma unroll
            for (int j = 0; j < 4; ++j) sc[kt][j] = 0.0f;
            const bf16x8 kf0 = *reinterpret_cast<const bf16x8*>(&Kd[cur][kt * 16 + lr][lg * 8]);
            const bf16x8 kf1 = *reinterpret_cast<const bf16x8*>(&Kd[cur][kt * 16 + lr][32 + lg * 8]);
            sc[kt] = __builtin_amdgcn_mfma_f32_16x16x32_bf16(kf0, qf[0], sc[kt], 0, 0, 0);
            sc[kt] = __builtin_amdgcn_mfma_f32_16x16x32_bf16(kf1, qf[1], sc[kt], 0, 0, 0);
        }
        __builtin_amdgcn_s_setprio(0);

        // fixed-max softmax: P = exp2(s*Cs - 48); pack bf16 into cc[kt]
        uint2 cc[4];
        #pragma unroll
        for (int kt = 0; kt < 4; ++kt) {
            bf16x4 pw;
            #pragma unroll
            for (int j = 0; j < 4; ++j) {
                const float e = exp2f(fmaf(sc[kt][j], Cs, -Ms));
                ls += e;
                pw[j] = (bf16_t)e;
            }
            cc[kt] = *reinterpret_cast<uint2*>(&pw);
        }

        // in-register P exchange: 4x4 block transpose across lanes {lr+16*lg}
        uint2 X0 = bq ? cc[1] : cc[0];
        uint2 X1 = bq ? cc[3] : cc[2];
        uint2 S0 = bq ? cc[0] : cc[1];
        uint2 S1 = bq ? cc[2] : cc[3];
        uint2 Y0, Y1;
        Y0.x = __shfl_xor(S0.x, 32); Y0.y = __shfl_xor(S0.y, 32);
        Y1.x = __shfl_xor(S1.x, 32); Y1.y = __shfl_xor(S1.y, 32);
        uint2 T0 = keepX ? Y0 : X0, T1 = keepX ? Y1 : X1;
        uint2 K0 = keepX ? X0 : Y0, K1 = keepX ? X1 : Y1;
        uint2 U0, U1;
        U0.x = __shfl_xor(T0.x, 16); U0.y = __shfl_xor(T0.y, 16);
        U1.x = __shfl_xor(T1.x, 16); U1.y = __shfl_xor(T1.y, 16);
        uint2 lo0 = odd ? U0 : K0, hi0 = odd ? K0 : U0;
        uint2 lo1 = odd ? U1 : K1, hi1 = odd ? K1 : U1;
        uint4 pb0u = {lo0.x, lo0.y, hi0.x, hi0.y};
        uint4 pb1u = {lo1.x, lo1.y, hi1.x, hi1.y};
        const bf16x8 pb0 = *reinterpret_cast<bf16x8*>(&pb0u);
        const bf16x8 pb1 = *reinterpret_cast<bf16x8*>(&pb1u);

        // PV: O^T = V^T * P^T
        __builtin_amdgcn_s_setprio(1);
        #pragma unroll
        for (int dt = 0; dt < 4; ++dt) {
            const bf16x8 vf0 = *reinterpret_cast<const bf16x8*>(&Vd[cur][dt * 16 + lr][lg * 8]);
            const bf16x8 vf1 = *reinterpret_cast<const bf16x8*>(&Vd[cur][dt * 16 + lr][32 + lg * 8]);
            oacc[dt] = __builtin_amdgcn_mfma_f32_16x16x32_bf16(vf0, pb0, oacc[dt], 0, 0, 0);
            oacc[dt] = __builtin_amdgcn_mfma_f32_16x16x32_bf16(vf1, pb1, oacc[dt], 0, 0, 0);
        }
        __builtin_amdgcn_s_setprio(0);

        // stage next tile into the other buffer; single barrier per tile
        if (more) {
            *reinterpret_cast<bf16x8*>(&Kd[cur ^ 1][kr][kc]) = kreg;
            #pragma unroll
            for (int j = 0; j < 4; ++j) {
                bf16x2 w; w[0] = vr0[j]; w[1] = vr1[j];
                *reinterpret_cast<bf16x2*>(&Vd[cur ^ 1][d0 + j][tp * 2]) = w;
            }
            __syncthreads();
        }
        cur ^= 1;
    }

    // write unnormalized partial O (bf16) + l
    ls += __shfl_xor(ls, 16);
    ls += __shfl_xor(ls, 32);
    const int r = (bh << 10) + q0 + (wave << 4) + lr;
    bf16_t* po = (half ? P1 : P0) + ((size_t)r << 6) + lg * 4;
    #pragma unroll
    for (int dt = 0; dt < 4; ++dt) {
        bf16x4 o;
        #pragma unroll
        for (int j = 0; j < 4; ++j) o[j] = (bf16_t)oacc[dt][j];
        *reinterpret_cast<bf16x4*>(po + dt * 16) = o;
    }
    if (lane < 16) lbuf[(half << 16) + r] = ls;
}

// ---------------------------------------------------------------------------
// combine the two T-half partials: Qb[row] = (P0 + P1) / (l0 + l1)
// row r = ((b*32+h)*1024+q); dest Qb[(b*1024+q)*2048 + h*64 + d]
// ---------------------------------------------------------------------------
__global__ __launch_bounds__(256)
void combine2(const bf16_t* __restrict__ p0, const bf16_t* __restrict__ p1,
              const float* __restrict__ lb, bf16_t* __restrict__ Qb)
{
    const int i = (blockIdx.x * 256 + threadIdx.x) * 8;   // 0 .. 4,194,304
    const int row = i >> 6;
    const float inv = 1.0f / (lb[row] + lb[65536 + row]);
    const bf16x8 a = *reinterpret_cast<const bf16x8*>(p0 + i);
    const bf16x8 c = *reinterpret_cast<const bf16x8*>(p1 + i);
    bf16x8 o;
    #pragma unroll
    for (int j = 0; j < 8; ++j)
        o[j] = (bf16_t)(((float)a[j] + (float)c[j]) * inv);
    const int bq = row >> 15, h = (row >> 10) & 31, q = row & 1023;
    *reinterpret_cast<bf16x8*>(
        Qb + ((size_t)((bq << 10) + q) << 11) + h * 64 + (i & 63)) = o;
}

// ---------------------------------------------------------------------------
extern "C" void kernel_launch(void* const* d_in, const int* in_sizes, int n_in,
                              void* d_out, int out_size, void* d_ws, size_t ws_size,
                              hipStream_t stream)
{
    const float* hs   = (const float*)d_in[0];
    const float* tctx = (const float*)d_in[1];
    const float* cosb = (const float*)d_in[2];
    const float* sinb = (const float*)d_in[3];
    const float* Wq   = (const float*)d_in[4];
    const float* Wk   = (const float*)d_in[5];
    const float* Wv   = (const float*)d_in[6];
    const float* Wo   = (const float*)d_in[7];
    const float* qg   = (const float*)d_in[8];
    const float* kg   = (const float*)d_in[9];
    float* out = (float*)d_out;

    // workspace layout (bf16 elems): total 23,068,672 elems = 46.1 MB
    bf16_t* W     = (bf16_t*)d_ws;
    bf16_t* kvinb = W;                    // [B][2048][2048] concat: 8,388,608
    bf16_t* Wqb   = kvinb + 8388608;      // Wq (4,194,304) + Wkv (2,097,152)
    bf16_t* Qb    = Wqb + 6291456;        // q buffer: 4,194,304
    bf16_t* KVb   = Qb + 4194304;         // k|v: 4,194,304
    // regions reused after gemm_qkv2 consumes them:
    bf16_t* Wob   = kvinb;                // Wo bf16 (first half of kvinb)
    bf16_t* Po0   = Wqb;                  // flash partial half0 (over Wq weights)
    bf16_t* Po1   = kvinb + 4194304;      // flash partial half1 (2nd half of kvinb)
    float*  lbuf  = (float*)(Wqb + 4194304);  // 131072 f32 (over Wkv weights)

    // converts
    cvt_concat2<<<4096, 256, 0, stream>>>(tctx, hs, kvinb);
    cvt_w3<<<3072, 256, 0, stream>>>(Wq, Wk, Wv, Wqb);

    // fused Q + KV projections with RMSNorm/RoPE epilogue (pipelined, XCD-swz)
    gemm_qkv2<<<512, 256, 0, stream>>>(kvinb, Wqb, Qb, KVb, qg, kg, cosb, sinb);

    // convert Wo into kvinb's space
    cvt_bf16<<<2048, 256, 0, stream>>>(Wo, Wob, 4194304);

    // flash attention, split-T partials (grid.z = half)
    flash_mfma<<<dim3(Bc * NH, Sq / 128, 2), 512, 0, stream>>>(Qb, KVb, Po0, Po1, lbuf);

    // combine halves -> bf16 attn into Qb
    combine2<<<2048, 256, 0, stream>>>(Po0, Po1, lbuf, Qb);

    // output projection: attn(bf16) @ Wo^T -> fp32 out
    gemm_out2<<<512, 256, 0, stream>>>(Qb, Wob, out);
}

// Round 10
// 153.295 us; speedup vs baseline: 1.5089x; 1.1119x over previous
//
#include <hip/hip_runtime.h>
#include <hip/hip_bf16.h>

// Problem constants
constexpr int Bc  = 2;
constexpr int Sq  = 1024;   // query seq len
constexpr int CTX = 1024;
constexpr int Tt  = 2048;   // total kv len
constexpr int HID = 2048;
constexpr int NH  = 32;
constexpr int NKV = 8;
constexpr int HD  = 64;

typedef __bf16 bf16_t;
typedef bf16_t bf16x8 __attribute__((ext_vector_type(8)));
typedef bf16_t bf16x4 __attribute__((ext_vector_type(4)));
typedef bf16_t bf16x2 __attribute__((ext_vector_type(2)));
typedef float  f32x4  __attribute__((ext_vector_type(4)));

// ---------------------------------------------------------------------------
// async global->LDS, 16B per lane (wave-uniform LDS base + lane*16)
// ---------------------------------------------------------------------------
__device__ __forceinline__ void gload16(const bf16_t* g, bf16_t* l)
{
    __builtin_amdgcn_global_load_lds(
        (const __attribute__((address_space(1))) void*)g,
        (__attribute__((address_space(3))) void*)l, 16, 0, 0);
}

// ---------------------------------------------------------------------------
// fp32 -> bf16 elementwise convert (8 elems/thread)
// ---------------------------------------------------------------------------
__global__ __launch_bounds__(256)
void cvt_bf16(const float* __restrict__ src, bf16_t* __restrict__ dst, int n)
{
    const int i = (blockIdx.x * 256 + threadIdx.x) * 8;
    if (i >= n) return;
    const float4 a = *reinterpret_cast<const float4*>(src + i);
    const float4 b = *reinterpret_cast<const float4*>(src + i + 4);
    bf16x8 o;
    o[0] = (bf16_t)a.x; o[1] = (bf16_t)a.y; o[2] = (bf16_t)a.z; o[3] = (bf16_t)a.w;
    o[4] = (bf16_t)b.x; o[5] = (bf16_t)b.y; o[6] = (bf16_t)b.z; o[7] = (bf16_t)b.w;
    *reinterpret_cast<bf16x8*>(dst + i) = o;
}

// fused Wq|Wk|Wv convert into contiguous dst (Wqb then Wkvb)
__global__ __launch_bounds__(256)
void cvt_w3(const float* __restrict__ wq, const float* __restrict__ wk,
            const float* __restrict__ wv, bf16_t* __restrict__ dst)
{
    const int i = (blockIdx.x * 256 + threadIdx.x) * 8;
    const float* src;
    int off;
    if (i < 4194304)      { src = wq; off = i; }
    else if (i < 5242880) { src = wk; off = i - 4194304; }
    else                  { src = wv; off = i - 5242880; }
    const float4 a = *reinterpret_cast<const float4*>(src + off);
    const float4 b = *reinterpret_cast<const float4*>(src + off + 4);
    bf16x8 o;
    o[0] = (bf16_t)a.x; o[1] = (bf16_t)a.y; o[2] = (bf16_t)a.z; o[3] = (bf16_t)a.w;
    o[4] = (bf16_t)b.x; o[5] = (bf16_t)b.y; o[6] = (bf16_t)b.z; o[7] = (bf16_t)b.w;
    *reinterpret_cast<bf16x8*>(dst + i) = o;
}

// fused concat + convert: dst [B][2048][2048] = concat(tctx, hs) per batch
__global__ __launch_bounds__(256)
void cvt_concat2(const float* __restrict__ tctx, const float* __restrict__ hs,
                 bf16_t* __restrict__ dst)
{
    const int i = (blockIdx.x * 256 + threadIdx.x) * 8;   // 0 .. 8M
    const int b = i >> 22;
    const int t = (i >> 11) & 2047;
    const int c = i & 2047;
    const float* src = (t < 1024) ? (tctx + ((size_t)(b * 1024 + t) << 11) + c)
                                  : (hs   + ((size_t)(b * 1024 + (t - 1024)) << 11) + c);
    const float4 a = *reinterpret_cast<const float4*>(src);
    const float4 d = *reinterpret_cast<const float4*>(src + 4);
    bf16x8 o;
    o[0] = (bf16_t)a.x; o[1] = (bf16_t)a.y; o[2] = (bf16_t)a.z; o[3] = (bf16_t)a.w;
    o[4] = (bf16_t)d.x; o[5] = (bf16_t)d.y; o[6] = (bf16_t)d.z; o[7] = (bf16_t)d.w;
    *reinterpret_cast<bf16x8*>(dst + i) = o;
}

// ---------------------------------------------------------------------------
// Fused QKV projection GEMM v2: BM=BN=128, BK=32, 256 thr (4 waves 2x2),
// 3-buffer LDS pipeline, prefetch distance 2, counted vmcnt (never 0 in loop),
// ONE barrier per K-step. XCD-swizzled block ids (512 blocks, chunk 64).
// RMSNorm/RoPE epilogue for Q and K. Q additionally scaled by
// Cs = 0.125*log2(e) so flash's softmax is a bare exp2 (scale folded here).
// ---------------------------------------------------------------------------
__global__ __launch_bounds__(256)
void gemm_qkv2(const bf16_t* __restrict__ Ain, const bf16_t* __restrict__ Wq_,
               bf16_t* __restrict__ Qo, bf16_t* __restrict__ KVo,
               const float* __restrict__ qg, const float* __restrict__ kg,
               const float* __restrict__ cosb, const float* __restrict__ sinb)
{
    __shared__ __align__(16) bf16_t Ads[3][4096];   // [128][32] x3
    __shared__ __align__(16) bf16_t Bds[3][4096];

    const int tid  = threadIdx.x;
    const int wave = tid >> 6;
    const int lane = tid & 63;

    // XCD-aware bijective swizzle: 512 blocks, 8 XCDs, 64-chunk.
    const int bid = blockIdx.x;
    const int swz = (bid & 7) * 64 + (bid >> 3);
    const bool isQ = swz < 256;
    int m0, n0, NN;
    const bf16_t* Bw;
    bf16_t* C;
    if (isQ) { m0 = (swz & 15) << 7; n0 = (swz >> 4) << 7; NN = 2048; Bw = Wq_;           C = Qo; }
    else     { const int kb = swz - 256;
               m0 = (kb & 31) << 7;  n0 = (kb >> 5) << 7;  NN = 1024; Bw = Wq_ + 4194304; C = KVo; }

    const int wm = (wave >> 1) << 6;   // 0,64
    const int wn = (wave & 1) << 6;    // 0,64
    const int lr = lane & 15;
    const int lg = lane >> 4;

    // staging: per wave 2 A-chunks + 2 B-chunks (16 rows x 32 cols each)
    const int sr = lane >> 2;          // 0..15
    const int sc = (lane & 3) << 3;    // 0,8,16,24
    size_t aoff[2], boff[2];
    #pragma unroll
    for (int cc = 0; cc < 2; ++cc) {
        const int am = m0 + wave * 32 + cc * 16 + sr;
        const int ar = isQ ? (((am >> 10) << 11) + 1024 + (am & 1023)) : am;
        aoff[cc] = (size_t)ar * HID + sc;
        boff[cc] = (size_t)(n0 + wave * 32 + cc * 16 + sr) * HID + sc;
    }

    f32x4 acc[4][4];
    #pragma unroll
    for (int i = 0; i < 4; ++i)
        #pragma unroll
        for (int j = 0; j < 4; ++j)
            #pragma unroll
            for (int r = 0; r < 4; ++r) acc[i][j][r] = 0.0f;

    auto STAGE = [&](int buf, int k0) {
        #pragma unroll
        for (int cc = 0; cc < 2; ++cc) {
            gload16(Ain + aoff[cc] + k0, &Ads[buf][(wave * 2 + cc) << 9]);
            gload16(Bw  + boff[cc] + k0, &Bds[buf][(wave * 2 + cc) << 9]);
        }
    };

    constexpr int nk = HID / 32;   // 64
    STAGE(0, 0);
    STAGE(1, 32);

    for (int t = 0; t < nk; ++t) {
        // wait tile t's 4 loads (tile t+1's 4 may remain in flight)
        if (t < nk - 1) asm volatile("s_waitcnt vmcnt(4)" ::: "memory");
        else            asm volatile("s_waitcnt vmcnt(0)" ::: "memory");
        __builtin_amdgcn_s_barrier();
        __builtin_amdgcn_sched_barrier(0);

        const int buf = t % 3;
        bf16x8 af[4], bfr[4];
        #pragma unroll
        for (int i = 0; i < 4; ++i) {
            af[i]  = *reinterpret_cast<const bf16x8*>(&Ads[buf][(wm + i * 16 + lr) * 32 + lg * 8]);
            bfr[i] = *reinterpret_cast<const bf16x8*>(&Bds[buf][(wn + i * 16 + lr) * 32 + lg * 8]);
        }
        asm volatile("s_waitcnt lgkmcnt(0)" ::: "memory");
        __builtin_amdgcn_sched_barrier(0);

        if (t + 2 < nk) STAGE((t + 2) % 3, (t + 2) * 32);

        __builtin_amdgcn_s_setprio(1);
        #pragma unroll
        for (int mi = 0; mi < 4; ++mi)
            #pragma unroll
            for (int ni = 0; ni < 4; ++ni)
                acc[mi][ni] = __builtin_amdgcn_mfma_f32_16x16x32_bf16(
                    af[mi], bfr[ni], acc[mi][ni], 0, 0, 0);
        __builtin_amdgcn_s_setprio(0);
    }

    // epilogue: RMSNorm + RoPE for Q part and K columns of KV part.
    const int emode = isQ ? 1 : (((n0 + wn) < 512) ? 2 : 0);
    if (emode) {
        const float* gamma = (emode == 1) ? qg : kg;
        // Q gets the softmax scale folded in (exact in the softmax ratio)
        const float post = (emode == 1) ? (0.125f * 1.44269504088896f) : 1.0f;
        float g4[4];
        #pragma unroll
        for (int ni = 0; ni < 4; ++ni) g4[ni] = gamma[ni * 16 + lr];

        #pragma unroll
        for (int mi = 0; mi < 4; ++mi)
            #pragma unroll
            for (int r = 0; r < 4; ++r) {
                const int m = m0 + wm + mi * 16 + lg * 4 + r;
                float ss = 0.0f;
                #pragma unroll
                for (int ni = 0; ni < 4; ++ni) ss += acc[mi][ni][r] * acc[mi][ni][r];
                ss += __shfl_xor(ss, 1);
                ss += __shfl_xor(ss, 2);
                ss += __shfl_xor(ss, 4);
                ss += __shfl_xor(ss, 8);
                const float rn = rsqrtf(ss * (1.0f / 64.0f) + 1e-6f);
                int bb, pos;
                if (emode == 1) { bb = m >> 10; pos = 1024 + (m & 1023); }
                else            { bb = m >> 11; pos = m & 2047; }
                const float* cp = cosb + (((size_t)bb * 2048 + pos) << 6);
                const float* sp = sinb + (((size_t)bb * 2048 + pos) << 6);
                float qn[4];
                #pragma unroll
                for (int ni = 0; ni < 4; ++ni) qn[ni] = acc[mi][ni][r] * rn * g4[ni];
                #pragma unroll
                for (int ni = 0; ni < 4; ++ni) {
                    const float rot = (ni < 2) ? -qn[ni + 2] : qn[ni - 2];
                    acc[mi][ni][r] = (qn[ni] * cp[ni * 16 + lr] + rot * sp[ni * 16 + lr]) * post;
                }
            }
    }

    #pragma unroll
    for (int mi = 0; mi < 4; ++mi)
        #pragma unroll
        for (int r = 0; r < 4; ++r) {
            const int m = m0 + wm + mi * 16 + lg * 4 + r;
            bf16_t* crow = C + (size_t)m * NN + n0 + wn + lr;
            crow[0]  = (bf16_t)acc[mi][0][r];
            crow[16] = (bf16_t)acc[mi][1][r];
            crow[32] = (bf16_t)acc[mi][2][r];
            crow[48] = (bf16_t)acc[mi][3][r];
        }
}

// ---------------------------------------------------------------------------
// Out-projection GEMM v2: C[m,n] = sum_k A[m,k]*B[n,k], fp32 C.
// M=N=K=2048 hardcoded. BM=64, BN=128, BK=32, same 3-buf counted-vmcnt
// pipeline, XCD swizzle (512 blocks, chunk 64).
// ---------------------------------------------------------------------------
__global__ __launch_bounds__(256)
void gemm_out2(const bf16_t* __restrict__ A, const bf16_t* __restrict__ Bw,
               float* __restrict__ C)
{
    __shared__ __align__(16) bf16_t Ads[3][2048];   // [64][32] x3
    __shared__ __align__(16) bf16_t Bds[3][4096];   // [128][32] x3

    const int tid  = threadIdx.x;
    const int wave = tid >> 6;
    const int lane = tid & 63;

    const int bid = blockIdx.x;
    const int swz = (bid & 7) * 64 + (bid >> 3);
    const int m0 = (swz & 31) << 6;   // 32 m-blocks
    const int n0 = (swz >> 5) << 7;   // 16 n-blocks

    const int wm = (wave >> 1) << 5;  // 0,32
    const int wn = (wave & 1) << 6;   // 0,64
    const int lr = lane & 15;
    const int lg = lane >> 4;

    const int sr = lane >> 2;
    const int sc = (lane & 3) << 3;

    const size_t aoff  = (size_t)(m0 + wave * 16 + sr) * HID + sc;
    size_t boff[2];
    #pragma unroll
    for (int cc = 0; cc < 2; ++cc)
        boff[cc] = (size_t)(n0 + wave * 32 + cc * 16 + sr) * HID + sc;

    f32x4 acc[2][4];
    #pragma unroll
    for (int i = 0; i < 2; ++i)
        #pragma unroll
        for (int j = 0; j < 4; ++j)
            #pragma unroll
            for (int r = 0; r < 4; ++r) acc[i][j][r] = 0.0f;

    auto STAGE = [&](int buf, int k0) {
        gload16(A + aoff + k0, &Ads[buf][wave << 9]);
        #pragma unroll
        for (int cc = 0; cc < 2; ++cc)
            gload16(Bw + boff[cc] + k0, &Bds[buf][(wave * 2 + cc) << 9]);
    };

    constexpr int nk = HID / 32;   // 64
    STAGE(0, 0);
    STAGE(1, 32);

    for (int t = 0; t < nk; ++t) {
        if (t < nk - 1) asm volatile("s_waitcnt vmcnt(3)" ::: "memory");
        else            asm volatile("s_waitcnt vmcnt(0)" ::: "memory");
        __builtin_amdgcn_s_barrier();
        __builtin_amdgcn_sched_barrier(0);

        const int buf = t % 3;
        bf16x8 af[2], bfr[4];
        #pragma unroll
        for (int i = 0; i < 2; ++i)
            af[i]  = *reinterpret_cast<const bf16x8*>(&Ads[buf][(wm + i * 16 + lr) * 32 + lg * 8]);
        #pragma unroll
        for (int i = 0; i < 4; ++i)
            bfr[i] = *reinterpret_cast<const bf16x8*>(&Bds[buf][(wn + i * 16 + lr) * 32 + lg * 8]);
        asm volatile("s_waitcnt lgkmcnt(0)" ::: "memory");
        __builtin_amdgcn_sched_barrier(0);

        if (t + 2 < nk) STAGE((t + 2) % 3, (t + 2) * 32);

        __builtin_amdgcn_s_setprio(1);
        #pragma unroll
        for (int mi = 0; mi < 2; ++mi)
            #pragma unroll
            for (int ni = 0; ni < 4; ++ni)
                acc[mi][ni] = __builtin_amdgcn_mfma_f32_16x16x32_bf16(
                    af[mi], bfr[ni], acc[mi][ni], 0, 0, 0);
        __builtin_amdgcn_s_setprio(0);
    }

    #pragma unroll
    for (int mi = 0; mi < 2; ++mi)
        #pragma unroll
        for (int r = 0; r < 4; ++r) {
            const int m = m0 + wm + mi * 16 + lg * 4 + r;
            float* crow = C + (size_t)m * 2048 + n0 + wn + lr;
            crow[0]  = acc[mi][0][r];
            crow[16] = acc[mi][1][r];
            crow[32] = acc[mi][2][r];
            crow[48] = acc[mi][3][r];
        }
}

// ---------------------------------------------------------------------------
// bf16 MFMA flash attention (r7 structure + minimal-VALU softmax).
// 8 waves (512 thr), QBLK=128, KV tile 64, double-buffered K/V with register
// prefetch, ONE barrier per tile, Pq exchanged via wave-local LDS (ds pipe,
// overlaps MFMA -- measured faster than shfl transpose in this VALU-bound
// regime, r7 vs r9). Q is pre-scaled by 0.125*log2e at the projection, and
// scores are bounded (|s*Cs| <= 46.6 < fp32-exp2 range), so softmax is a
// BARE exp2 -- no max, no shift; the 2^bias cancels in O = sum(Pv)/sum(P).
// Row-sum l computed on the MATRIX pipe via a ones-fragment MFMA (lane's
// C-col == its q-row -> no cross-lane reduce at all).
// Grid: (B*NH, Sq/128). Output bf16 in place over Q.
// ---------------------------------------------------------------------------
__global__ __launch_bounds__(512)
void flash_mfma(const bf16_t* __restrict__ Qb, const bf16_t* __restrict__ KVb,
                bf16_t* __restrict__ Ob)
{
    const int bh = blockIdx.x;
    const int b  = bh >> 5;
    const int h  = bh & 31;
    const int g  = h >> 2;
    const int q0 = blockIdx.y << 7;
    const int tid  = threadIdx.x;
    const int wave = tid >> 6;
    const int lane = tid & 63;
    const int lr = lane & 15;
    const int lg = lane >> 4;

    __shared__ __align__(16) bf16_t Kd[2][64][68];      // [k][d]
    __shared__ __align__(16) bf16_t Vd[2][64][68];      // [d][t]
    __shared__ __align__(16) bf16_t Pq[8][16][68];      // per-wave [q][t]

    // staging assignment (block-wide, 512 threads)
    const int kr = tid >> 3;            // K row 0..63
    const int kc = (tid & 7) << 3;      // K col 0,8,..,56
    const int tp = tid >> 4;            // V t-pair 0..31
    const int d0 = (tid & 15) << 2;     // V d-group

    const size_t kbase = (size_t)(b * Tt) * 1024 + g * 64;

    // Q fragments (B-operand of S^T = K*Q^T); Q pre-scaled by Cs.
    bf16x8 qf[2];
    {
        const bf16_t* qp = Qb + (size_t)(b * Sq + q0 + wave * 16 + lr) * 2048 + h * 64 + lg * 8;
        qf[0] = *reinterpret_cast<const bf16x8*>(qp);
        qf[1] = *reinterpret_cast<const bf16x8*>(qp + 32);
    }

    // ones fragment for the l row-sum MFMA
    bf16x8 onesf;
    #pragma unroll
    for (int j = 0; j < 8; ++j) onesf[j] = (bf16_t)1.0f;

    f32x4 lacc;
    #pragma unroll
    for (int j = 0; j < 4; ++j) lacc[j] = 0.0f;
    f32x4 oacc[4];
    #pragma unroll
    for (int dt = 0; dt < 4; ++dt)
        #pragma unroll
        for (int j = 0; j < 4; ++j) oacc[dt][j] = 0.0f;

    // prologue: load tile 0 into regs, write buf 0
    bf16x8 kreg;
    bf16x4 vr0, vr1;
    {
        kreg = *reinterpret_cast<const bf16x8*>(KVb + kbase + (size_t)kr * 1024 + kc);
        const bf16_t* vp = KVb + kbase + (size_t)(tp * 2) * 1024 + 512 + d0;
        vr0 = *reinterpret_cast<const bf16x4*>(vp);
        vr1 = *reinterpret_cast<const bf16x4*>(vp + 1024);
    }
    *reinterpret_cast<bf16x8*>(&Kd[0][kr][kc]) = kreg;
    #pragma unroll
    for (int j = 0; j < 4; ++j) {
        bf16x2 w; w[0] = vr0[j]; w[1] = vr1[j];
        *reinterpret_cast<bf16x2*>(&Vd[0][d0 + j][tp * 2]) = w;
    }
    __syncthreads();

    int cur = 0;

    for (int t0 = 0; t0 < Tt; t0 += 64) {
        const bool more = (t0 + 64 < Tt);
        if (more) {
            const size_t tb = kbase + (size_t)(t0 + 64) * 1024;
            kreg = *reinterpret_cast<const bf16x8*>(KVb + tb + (size_t)kr * 1024 + kc);
            const bf16_t* vp = KVb + tb + (size_t)(tp * 2) * 1024 + 512 + d0;
            vr0 = *reinterpret_cast<const bf16x4*>(vp);
            vr1 = *reinterpret_cast<const bf16x4*>(vp + 1024);
        }

        // QK^T (swapped): S^T = K * Q^T (already in log2 units)
        f32x4 sc[4];
        __builtin_amdgcn_s_setprio(1);
        #pragma unroll
        for (int kt = 0; kt < 4; ++kt) {
            #pragma unroll
            for (int j = 0; j < 4; ++j) sc[kt][j] = 0.0f;
            const bf16x8 kf0 = *reinterpret_cast<const bf16x8*>(&Kd[cur][kt * 16 + lr][lg * 8]);
            const bf16x8 kf1 = *reinterpret_cast<const bf16x8*>(&Kd[cur][kt * 16 + lr][32 + lg * 8]);
            sc[kt] = __builtin_amdgcn_mfma_f32_16x16x32_bf16(kf0, qf[0], sc[kt], 0, 0, 0);
            sc[kt] = __builtin_amdgcn_mfma_f32_16x16x32_bf16(kf1, qf[1], sc[kt], 0, 0, 0);
        }
        __builtin_amdgcn_s_setprio(0);

        // bare-exp2 softmax: P = exp2(s); write bf16 P to per-wave LDS
        #pragma unroll
        for (int kt = 0; kt < 4; ++kt) {
            bf16x4 pw;
            #pragma unroll
            for (int j = 0; j < 4; ++j) pw[j] = (bf16_t)exp2f(sc[kt][j]);
            *reinterpret_cast<bf16x4*>(&Pq[wave][lr][kt * 16 + lg * 4]) = pw;
        }

        // PV: O^T = V^T * P^T, plus l = ones * P^T (row-sum on matrix pipe)
        bf16x8 pb[2];
        pb[0] = *reinterpret_cast<const bf16x8*>(&Pq[wave][lr][lg * 8]);
        pb[1] = *reinterpret_cast<const bf16x8*>(&Pq[wave][lr][32 + lg * 8]);
        __builtin_amdgcn_s_setprio(1);
        #pragma unroll
        for (int dt = 0; dt < 4; ++dt) {
            const bf16x8 vf0 = *reinterpret_cast<const bf16x8*>(&Vd[cur][dt * 16 + lr][lg * 8]);
            const bf16x8 vf1 = *reinterpret_cast<const bf16x8*>(&Vd[cur][dt * 16 + lr][32 + lg * 8]);
            oacc[dt] = __builtin_amdgcn_mfma_f32_16x16x32_bf16(vf0, pb[0], oacc[dt], 0, 0, 0);
            oacc[dt] = __builtin_amdgcn_mfma_f32_16x16x32_bf16(vf1, pb[1], oacc[dt], 0, 0, 0);
        }
        lacc = __builtin_amdgcn_mfma_f32_16x16x32_bf16(onesf, pb[0], lacc, 0, 0, 0);
        lacc = __builtin_amdgcn_mfma_f32_16x16x32_bf16(onesf, pb[1], lacc, 0, 0, 0);
        __builtin_amdgcn_s_setprio(0);

        // stage next tile into the other buffer; single barrier per tile
        if (more) {
            *reinterpret_cast<bf16x8*>(&Kd[cur ^ 1][kr][kc]) = kreg;
            #pragma unroll
            for (int j = 0; j < 4; ++j) {
                bf16x2 w; w[0] = vr0[j]; w[1] = vr1[j];
                *reinterpret_cast<bf16x2*>(&Vd[cur ^ 1][d0 + j][tp * 2]) = w;
            }
            __syncthreads();
        }
        cur ^= 1;
    }

    // finalize: l for q=lr is in every element of lacc (no reduce needed)
    const float inv = 1.0f / lacc[0];
    #pragma unroll
    for (int dt = 0; dt < 4; ++dt) {
        bf16x4 o;
        #pragma unroll
        for (int j = 0; j < 4; ++j) o[j] = (bf16_t)(oacc[dt][j] * inv);
        *reinterpret_cast<bf16x4*>(
            Ob + (size_t)(b * Sq + q0 + wave * 16 + lr) * 2048 + h * 64 + dt * 16 + lg * 4) = o;
    }
}

// ---------------------------------------------------------------------------
extern "C" void kernel_launch(void* const* d_in, const int* in_sizes, int n_in,
                              void* d_out, int out_size, void* d_ws, size_t ws_size,
                              hipStream_t stream)
{
    const float* hs   = (const float*)d_in[0];
    const float* tctx = (const float*)d_in[1];
    const float* cosb = (const float*)d_in[2];
    const float* sinb = (const float*)d_in[3];
    const float* Wq   = (const float*)d_in[4];
    const float* Wk   = (const float*)d_in[5];
    const float* Wv   = (const float*)d_in[6];
    const float* Wo   = (const float*)d_in[7];
    const float* qg   = (const float*)d_in[8];
    const float* kg   = (const float*)d_in[9];
    float* out = (float*)d_out;

    // workspace layout (bf16 elems): total 23,068,672 elems = 46.1 MB
    bf16_t* W     = (bf16_t*)d_ws;
    bf16_t* kvinb = W;                    // [B][2048][2048] concat: 8,388,608
    bf16_t* Wqb   = kvinb + 8388608;      // Wq (4,194,304) + Wkv (2,097,152)
    bf16_t* Qb    = Wqb + 6291456;        // q / attn in-place: 4,194,304
    bf16_t* KVb   = Qb + 4194304;         // k|v: 4,194,304
    bf16_t* Wob   = kvinb;                // reused after gemm_qkv2 consumes kvinb

    // converts
    cvt_concat2<<<4096, 256, 0, stream>>>(tctx, hs, kvinb);
    cvt_w3<<<3072, 256, 0, stream>>>(Wq, Wk, Wv, Wqb);

    // fused Q + KV projections with RMSNorm/RoPE(+Cs on Q) epilogue
    gemm_qkv2<<<512, 256, 0, stream>>>(kvinb, Wqb, Qb, KVb, qg, kg, cosb, sinb);

    // convert Wo into kvinb's space
    cvt_bf16<<<2048, 256, 0, stream>>>(Wo, Wob, 4194304);

    // flash attention (bf16 MFMA), bf16 output in place over Q
    flash_mfma<<<dim3(Bc * NH, Sq / 128), 512, 0, stream>>>(Qb, KVb, Qb);

    // output projection: attn(bf16) @ Wo^T -> fp32 out
    gemm_out2<<<512, 256, 0, stream>>>(Qb, Wob, out);
}